// Round 2
// baseline (502.058 us; speedup 1.0000x reference)
//
#include <hip/hip_runtime.h>

// ---------------- problem constants ----------------
constexpr int N_NODES  = 50000;
constexpr int N_EDGES  = 800000;
constexpr int N_GRAPHS = 512;
constexpr int F_IN     = 128;
constexpr int HID      = 256;
constexpr int NPAD     = 50048;   // 391*128 padded rows

typedef short short8 __attribute__((ext_vector_type(8)));
typedef float f32x4  __attribute__((ext_vector_type(4)));
typedef unsigned int u32x4 __attribute__((ext_vector_type(4)));

// bf16 helpers (raw ushort storage; RNE rounding)
__device__ __forceinline__ unsigned short f2b(float f) {
    unsigned u = __float_as_uint(f);
    u += 0x7fffu + ((u >> 16) & 1u);
    return (unsigned short)(u >> 16);
}
__device__ __forceinline__ float b2f_lo(unsigned u) { return __uint_as_float(u << 16); }
__device__ __forceinline__ float b2f_hi(unsigned u) { return __uint_as_float(u & 0xffff0000u); }

// ---------------- fused prep: deg histogram + x->bf16 (chunk-major) + weights -> B-fragment ----------------
// x_bf chunk-major layout: [4][NPAD][32] bf16, chunk c owns features [32c, 32c+32)
// Wt_frag short index: half*(K*128) + ((k>>3)*128 + (n&127))*8 + (k&7), half = n>>7
__global__ __launch_bounds__(256) void prep_kernel(
    const int* __restrict__ dst, int* __restrict__ deg,
    const float* __restrict__ x, unsigned short* __restrict__ x_bf,
    const float* __restrict__ W0, const float* __restrict__ W1, const float* __restrict__ W2,
    unsigned short* __restrict__ Wt0, unsigned short* __restrict__ Wt1, unsigned short* __restrict__ Wt2)
{
    const int b = blockIdx.x, t = threadIdx.x;
    if (b < 3125) {
        int e = b * 256 + t;                       // 3125*256 == 800000
        atomicAdd(&deg[dst[e]], 1);
    } else if (b < 9375) {
        int i = (b - 3125) * 256 + t;              // 6250*256 == 1.6M float4
        float4 v = *reinterpret_cast<const float4*>(x + (size_t)i * 4);
        unsigned r0 = (unsigned)f2b(v.x) | ((unsigned)f2b(v.y) << 16);
        unsigned r1 = (unsigned)f2b(v.z) | ((unsigned)f2b(v.w) << 16);
        // i -> node = i>>5, chunk = (i&31)>>3, uint2-slot = i&7
        int node = i >> 5, c = (i & 31) >> 3, slot = i & 7;
        *reinterpret_cast<uint2*>(x_bf + (((size_t)c * NPAD + node) << 5) + slot * 4) =
            make_uint2(r0, r1);
    } else {
        int i = (b - 9375) * 256 + t;              // 640*256 == 163840
        const float* W; unsigned short* Wt; int K; int j;
        if (i < 32768)      { W = W0; Wt = Wt0; K = 128; j = i; }
        else if (i < 98304) { W = W1; Wt = Wt1; K = 256; j = i - 32768; }
        else                { W = W2; Wt = Wt2; K = 256; j = i - 98304; }
        int k = j >> 8, n = j & 255;
        int idx = (n >> 7) * (K * 128) + (((k >> 3) * 128 + (n & 127)) << 3) + (k & 7);
        Wt[idx] = f2b(W[j]);
    }
}

// ---------------- parallel scan (3 kernels) + dis fused ----------------
__global__ void block_sum_dis_kernel(const int* __restrict__ deg, int* __restrict__ bsum,
                                     float* __restrict__ dis, int n) {
    __shared__ int sm[256];
    int t = threadIdx.x, base = blockIdx.x * 1024;
    int s = 0;
    #pragma unroll
    for (int i = 0; i < 4; ++i) {
        int idx = base + t + i * 256;
        if (idx < n) { int d = deg[idx]; s += d; dis[idx] = rsqrtf((float)d + 1.0f); }
    }
    sm[t] = s; __syncthreads();
    for (int o = 128; o > 0; o >>= 1) { if (t < o) sm[t] += sm[t + o]; __syncthreads(); }
    if (t == 0) bsum[blockIdx.x] = sm[0];
}

__global__ void scan_bsum_kernel(int* __restrict__ bsum, int nb) {   // 1 block, 64 threads
    __shared__ int sm[64];
    int t = threadIdx.x;
    int v = (t < nb) ? bsum[t] : 0;
    sm[t] = v; __syncthreads();
    for (int o = 1; o < 64; o <<= 1) {
        int a = (t >= o) ? sm[t - o] : 0; __syncthreads();
        sm[t] += a; __syncthreads();
    }
    if (t < nb) bsum[t] = sm[t] - v;   // exclusive
}

__global__ void scan_local_kernel(const int* __restrict__ deg, const int* __restrict__ bsum,
                                  int* __restrict__ row_start, int* __restrict__ cursor, int n) {
    __shared__ int sm[256];
    int t = threadIdx.x, base = blockIdx.x * 1024;
    int idx0 = base + t * 4;
    int v[4], s = 0;
    #pragma unroll
    for (int i = 0; i < 4; ++i) { int id = idx0 + i; v[i] = (id < n) ? deg[id] : 0; s += v[i]; }
    sm[t] = s; __syncthreads();
    for (int o = 1; o < 256; o <<= 1) {
        int a = (t >= o) ? sm[t - o] : 0; __syncthreads();
        sm[t] += a; __syncthreads();
    }
    int excl = bsum[blockIdx.x] + sm[t] - s;
    #pragma unroll
    for (int i = 0; i < 4; ++i) {
        int id = idx0 + i;
        if (id < n) { row_start[id] = excl; cursor[id] = excl; }
        excl += v[i];
    }
    if (blockIdx.x == gridDim.x - 1 && t == 255) row_start[n] = excl;  // == N_EDGES
}

// ---------------- CSR scatter: entry = u16 src only (N_NODES < 65536) ----------------
__global__ void fill_csr(const int* __restrict__ src, const int* __restrict__ dst,
                         int* __restrict__ cursor, unsigned short* __restrict__ csr16) {
    int e = blockIdx.x * blockDim.x + threadIdx.x;
    if (e >= N_EDGES) return;
    int d = dst[e];
    int pos = atomicAdd(&cursor[d], 1);
    csr16[pos] = (unsigned short)src[e];
}

// ---------------- XCD-resident chunked aggregation ----------------
// hin chunk-major [NC][NPAD][32] bf16; chunk routed to an XCD via blockIdx%8 so the
// 50000x64B = 3.2MB chunk table stays resident in that XCD's 4MB L2.
// Each 4-lane group owns one node's 64B chunk slice: no cross-lane reduction at all.
// Output: MFMA-A-fragment layout, 16B chunk index fcg = chunk*4 + fl.
__device__ __forceinline__ void fma8(float* acc, uint4 g, float wt) {
    acc[0] = fmaf(b2f_lo(g.x), wt, acc[0]); acc[1] = fmaf(b2f_hi(g.x), wt, acc[1]);
    acc[2] = fmaf(b2f_lo(g.y), wt, acc[2]); acc[3] = fmaf(b2f_hi(g.y), wt, acc[3]);
    acc[4] = fmaf(b2f_lo(g.z), wt, acc[4]); acc[5] = fmaf(b2f_hi(g.z), wt, acc[5]);
    acc[6] = fmaf(b2f_lo(g.w), wt, acc[6]); acc[7] = fmaf(b2f_hi(g.w), wt, acc[7]);
}

template<int F>
__global__ __launch_bounds__(256) void agg_chunked(
    const unsigned short* __restrict__ hin,
    const int* __restrict__ row_start,
    const unsigned short* __restrict__ csr_src,
    const float* __restrict__ dis,
    uint4* __restrict__ out4)
{
    const int gid = blockIdx.x;
    int chunk, nb;
    if (F == 256) {            // 8 chunks, one per XCD; 782 node-blocks per chunk
        chunk = gid & 7; nb = gid >> 3;
    } else {                   // 4 chunks, each duplicated on 2 XCDs over node halves
        int s = gid & 7; chunk = s & 3; nb = (s >> 2) * 391 + (gid >> 3);
    }
    const int t    = threadIdx.x;
    const int node = nb * 64 + (t >> 2);    // 64 nodes per block, 4 lanes per node
    const int fl   = t & 3;                 // which 16B of the 64B chunk slice
    if (node >= N_NODES) return;

    const uint4* hc = reinterpret_cast<const uint4*>(hin) + (size_t)chunk * (NPAD * 4);

    const float dn = dis[node];
    float acc[8];
    {   // self-loop term
        uint4 sv = hc[(node << 2) + fl];
        float sw = dn * dn;
        acc[0] = b2f_lo(sv.x) * sw; acc[1] = b2f_hi(sv.x) * sw;
        acc[2] = b2f_lo(sv.y) * sw; acc[3] = b2f_hi(sv.y) * sw;
        acc[4] = b2f_lo(sv.z) * sw; acc[5] = b2f_hi(sv.z) * sw;
        acc[6] = b2f_lo(sv.w) * sw; acc[7] = b2f_hi(sv.w) * sw;
    }

    int j = row_start[node];
    const int end = row_start[node + 1];
    for (; j + 4 <= end; j += 4) {
        int s0 = __builtin_nontemporal_load(&csr_src[j + 0]);
        int s1 = __builtin_nontemporal_load(&csr_src[j + 1]);
        int s2 = __builtin_nontemporal_load(&csr_src[j + 2]);
        int s3 = __builtin_nontemporal_load(&csr_src[j + 3]);
        uint4 g0 = hc[(s0 << 2) + fl];
        uint4 g1 = hc[(s1 << 2) + fl];
        uint4 g2 = hc[(s2 << 2) + fl];
        uint4 g3 = hc[(s3 << 2) + fl];
        float w0 = dis[s0] * dn, w1 = dis[s1] * dn, w2 = dis[s2] * dn, w3 = dis[s3] * dn;
        fma8(acc, g0, w0); fma8(acc, g1, w1); fma8(acc, g2, w2); fma8(acc, g3, w3);
    }
    for (; j < end; ++j) {
        int s0 = __builtin_nontemporal_load(&csr_src[j]);
        uint4 g0 = hc[(s0 << 2) + fl];
        float w0 = dis[s0] * dn;
        fma8(acc, g0, w0);
    }

    u32x4 r;
    r.x = (unsigned)f2b(acc[0]) | ((unsigned)f2b(acc[1]) << 16);
    r.y = (unsigned)f2b(acc[2]) | ((unsigned)f2b(acc[3]) << 16);
    r.z = (unsigned)f2b(acc[4]) | ((unsigned)f2b(acc[5]) << 16);
    r.w = (unsigned)f2b(acc[6]) | ((unsigned)f2b(acc[7]) << 16);
    const int fcg = chunk * 4 + fl;
    __builtin_nontemporal_store(
        r, reinterpret_cast<u32x4*>(
               &out4[(size_t)(node >> 7) * (128 * (F / 8)) + fcg * 128 + (node & 127)]));
}

// ---------------- MFMA GEMM, fragment-direct A, full weight-half resident in LDS ----------------
// A in fragment layout [panel][kchunk][row][8]; Wt_frag in [half][kchunk][col][8].
// C output chunk-major [8][NPAD][32] bf16 (feeds agg_chunked / pool).
// grid (NPAD/128, 2); 256 threads = 4 waves (2x2 of 64x64). One barrier total.
template<int K>
__global__ __launch_bounds__(256) void gemm_frag(
    const uint4* __restrict__ A4,
    const unsigned short* __restrict__ Wt_frag,
    const float* __restrict__ bias,
    unsigned short* __restrict__ C,
    int relu)
{
    __shared__ __align__(16) unsigned short Bs[K * 128];   // 64 KB (K=256) / 32 KB (K=128)
    const int t    = threadIdx.x;
    const int lane = t & 63;
    const int w    = t >> 6;
    const int wm   = w & 1, wn = w >> 1;
    const int q    = lane >> 4, m = lane & 15;
    const int panel = blockIdx.x;
    const int col0  = blockIdx.y * 128;

    // stage the whole 128-col weight half: contiguous, coalesced, conflict-free
    {
        const uint4* src4 = reinterpret_cast<const uint4*>(Wt_frag + blockIdx.y * (K * 128));
        uint4* dst4 = reinterpret_cast<uint4*>(Bs);
        #pragma unroll
        for (int it = 0; it < K / 16; ++it)
            dst4[it * 256 + t] = src4[it * 256 + t];
    }
    __syncthreads();

    f32x4 acc[4][4] = {};
    const int abase = panel * (128 * (K / 8));

    #pragma unroll
    for (int kb = 0; kb < K / 32; ++kb) {
        short8 af[4], bf[4];
        #pragma unroll
        for (int i = 0; i < 4; ++i) {
            uint4 v = A4[abase + (kb * 4 + q) * 128 + wm * 64 + i * 16 + m];
            af[i] = *reinterpret_cast<short8*>(&v);
        }
        #pragma unroll
        for (int jn = 0; jn < 4; ++jn)
            bf[jn] = *reinterpret_cast<const short8*>(&Bs[((kb * 4 + q) * 128 + wn * 64 + jn * 16 + m) * 8]);
        #pragma unroll
        for (int i = 0; i < 4; ++i)
            #pragma unroll
            for (int jn = 0; jn < 4; ++jn)
                acc[i][jn] = __builtin_amdgcn_mfma_f32_16x16x32_bf16(af[i], bf[jn], acc[i][jn], 0, 0, 0);
    }

    // epilogue: C/D layout col = lane&15, row = (lane>>4)*4 + reg; chunk-major bf16 out
    #pragma unroll
    for (int jn = 0; jn < 4; ++jn) {
        int col = col0 + wn * 64 + jn * 16 + m;
        float bj = bias[col];
        int cch = col >> 5, o = col & 31;
        #pragma unroll
        for (int i = 0; i < 4; ++i) {
            int rowb = panel * 128 + wm * 64 + i * 16 + q * 4;
            #pragma unroll
            for (int r = 0; r < 4; ++r) {
                float v = acc[i][jn][r] + bj;
                if (relu) v = fmaxf(v, 0.f);
                C[((size_t)cch * NPAD + (rowb + r)) * 32 + o] = f2b(v);
            }
        }
    }
}

// ---------------- fused pool + MLP head (h is chunk-major [8][NPAD][32]) ----------------
__global__ __launch_bounds__(256) void pool_mlp_kernel(
    const unsigned short* __restrict__ h, const int* __restrict__ batch,
    const float* __restrict__ Wm1, const float* __restrict__ bm1,
    const float* __restrict__ Wm2, const float* __restrict__ bm2,
    float* __restrict__ out)
{
    __shared__ float p[HID];
    __shared__ float red[HID];
    __shared__ int se[2];
    const int g = blockIdx.x, t = threadIdx.x;
    if (t < 2) {
        int target = g + t;
        int lo = 0, hi = N_NODES;
        while (lo < hi) { int mid = (lo + hi) >> 1; if (batch[mid] < target) lo = mid + 1; else hi = mid; }
        se[t] = lo;
    }
    __syncthreads();
    const int s = se[0], e = se[1];
    const size_t cbase = (size_t)(t >> 5) * NPAD * 32 + (t & 31);
    float acc = 0.f;
    for (int n = s; n < e; ++n) acc += b2f_lo((unsigned)h[cbase + (size_t)n * 32]);
    p[t] = acc / fmaxf((float)(e - s), 1.0f);
    __syncthreads();
    float a2 = bm1[t];
    for (int k = 0; k < HID; ++k) a2 = fmaf(p[k], Wm1[k * HID + t], a2);
    red[t] = fmaxf(a2, 0.f) * Wm2[t];
    __syncthreads();
    for (int o = 128; o > 0; o >>= 1) {
        if (t < o) red[t] += red[t + o];
        __syncthreads();
    }
    if (t == 0) out[g] = red[0] + bm2[0];
}

// ---------------- launch ----------------
extern "C" void kernel_launch(void* const* d_in, const int* in_sizes, int n_in,
                              void* d_out, int out_size, void* d_ws, size_t ws_size,
                              hipStream_t stream) {
    const float* x    = (const float*)d_in[0];
    const int*   ei   = (const int*)d_in[1];
    const int*   batch= (const int*)d_in[2];
    const float* W0   = (const float*)d_in[3];
    const float* b0   = (const float*)d_in[4];
    const float* W1   = (const float*)d_in[5];
    const float* b1   = (const float*)d_in[6];
    const float* W2   = (const float*)d_in[7];
    const float* b2   = (const float*)d_in[8];
    const float* Wm1  = (const float*)d_in[9];
    const float* bm1  = (const float*)d_in[10];
    const float* Wm2  = (const float*)d_in[11];
    const float* bm2  = (const float*)d_in[12];
    float* out = (float*)d_out;

    char* ws = (char*)d_ws;
    size_t off = 0;
    auto alloc = [&](size_t bytes) -> void* {
        void* p = ws + off;
        off += (bytes + 255) & ~(size_t)255;
        return p;
    };
    int*   deg       = (int*)  alloc((size_t)N_NODES * 4);
    float* dis       = (float*)alloc((size_t)N_NODES * 4);
    int*   row_start = (int*)  alloc((size_t)(N_NODES + 1) * 4);
    int*   cursor    = (int*)  alloc((size_t)N_NODES * 4);
    int*   bsum      = (int*)  alloc((size_t)64 * 4);
    unsigned short* csr16 = (unsigned short*)alloc((size_t)N_EDGES * 2);
    unsigned short* x_bf  = (unsigned short*)alloc((size_t)NPAD * F_IN * 2);   // [4][NPAD][32]
    unsigned short* Wt0   = (unsigned short*)alloc((size_t)F_IN * HID * 2);
    unsigned short* Wt1   = (unsigned short*)alloc((size_t)HID * HID * 2);
    unsigned short* Wt2   = (unsigned short*)alloc((size_t)HID * HID * 2);
    unsigned short* bufA  = (unsigned short*)alloc((size_t)NPAD * HID * 2);    // fragment layout
    unsigned short* bufB  = (unsigned short*)alloc((size_t)NPAD * HID * 2);    // [8][NPAD][32]

    const int* src = ei;
    const int* dst = ei + N_EDGES;
    const int NB = (N_NODES + 1023) / 1024;   // 49

    hipMemsetAsync(deg, 0, (size_t)N_NODES * 4, stream);
    prep_kernel         <<<10015, 256, 0, stream>>>(dst, deg, x, x_bf, W0, W1, W2, Wt0, Wt1, Wt2);
    block_sum_dis_kernel<<<NB, 256, 0, stream>>>(deg, bsum, dis, N_NODES);
    scan_bsum_kernel    <<<1, 64, 0, stream>>>(bsum, NB);
    scan_local_kernel   <<<NB, 256, 0, stream>>>(deg, bsum, row_start, cursor, N_NODES);
    fill_csr            <<<(N_EDGES + 255) / 256, 256, 0, stream>>>(src, dst, cursor, csr16);

    dim3 ggrid(NPAD / 128, 2);

    // layer 0: chunked agg (4 chunks x 2 halves -> 8 XCD slots) -> fragment GEMM -> chunk-major out
    agg_chunked<F_IN><<<391 * 8, 256, 0, stream>>>(x_bf, row_start, csr16, dis, (uint4*)bufA);
    gemm_frag<F_IN><<<ggrid, 256, 0, stream>>>((const uint4*)bufA, Wt0, b0, bufB, 1);

    agg_chunked<HID><<<782 * 8, 256, 0, stream>>>(bufB, row_start, csr16, dis, (uint4*)bufA);
    gemm_frag<HID><<<ggrid, 256, 0, stream>>>((const uint4*)bufA, Wt1, b1, bufB, 1);

    agg_chunked<HID><<<782 * 8, 256, 0, stream>>>(bufB, row_start, csr16, dis, (uint4*)bufA);
    gemm_frag<HID><<<ggrid, 256, 0, stream>>>((const uint4*)bufA, Wt2, b2, bufB, 1);

    pool_mlp_kernel<<<N_GRAPHS, HID, 0, stream>>>(bufB, batch, Wm1, bm1, Wm2, bm2, out);
}